// Round 9
// baseline (274.759 us; speedup 1.0000x reference)
//
#include <hip/hip_runtime.h>

// L2Q attention, fp16-MFMA. B=8, N=1024, C=768, H=12, d=64, 3C=2304, M=8192.
// R9: qkv GEMM -> fragment-major LDS (0 bank conflicts), BK=64, LDS-transpose
//     epilogue (contiguous 128B stores for q/k and v^T). attn writes hi/lo
//     split output pair so proj stages A via global_load_lds (no in-register
//     split). proj -> async16-staged, fragment-major, BK=64, 3-term split.

typedef _Float16 f16x8 __attribute__((ext_vector_type(8)));
typedef _Float16 f16x4 __attribute__((ext_vector_type(4)));
typedef float f32x4 __attribute__((ext_vector_type(4)));

#define NB 8
#define NN 1024
#define NC 768
#define NH 12
#define ND 64
#define TC 2304
#define NM 8192

__device__ __forceinline__ void async16(const void* g, void* l) {
    __builtin_amdgcn_global_load_lds(
        (const __attribute__((address_space(1))) void*)g,
        (__attribute__((address_space(3))) void*)l, 16, 0, 0);
}

// ---------------- fp32 -> fp16 convert ----------------
__global__ void cvt_f32_f16(const float* __restrict__ s, _Float16* __restrict__ d, int n4) {
    int i = blockIdx.x * 256 + threadIdx.x;
    if (i < n4) {
        float4 v = ((const float4*)s)[i];
        f16x4 o;
        o[0] = (_Float16)v.x; o[1] = (_Float16)v.y;
        o[2] = (_Float16)v.z; o[3] = (_Float16)v.w;
        ((f16x4*)d)[i] = o;
    }
}

// ---------------- fp32 -> fp16 hi/lo split (proj weights) ----------------
__global__ void cvt_split_f32(const float* __restrict__ s, _Float16* __restrict__ hi,
                              _Float16* __restrict__ lo, int n4) {
    int i = blockIdx.x * 256 + threadIdx.x;
    if (i < n4) {
        float4 v = ((const float4*)s)[i];
        f16x4 h, l;
        h[0] = (_Float16)v.x; l[0] = (_Float16)(v.x - (float)h[0]);
        h[1] = (_Float16)v.y; l[1] = (_Float16)(v.y - (float)h[1]);
        h[2] = (_Float16)v.z; l[2] = (_Float16)(v.z - (float)h[2]);
        h[3] = (_Float16)v.w; l[3] = (_Float16)(v.w - (float)h[3]);
        ((f16x4*)hi)[i] = h;
        ((f16x4*)lo)[i] = l;
    }
}

// ---------------- qkv GEMM: C[8192,2304] = X16 * Wqkv16^T ----------------
// 128x128 tile, BK=64, fragment-major LDS, LDS-transpose epilogue.
__global__ __launch_bounds__(256) void gemm_qkv(
    const _Float16* __restrict__ Ah, const _Float16* __restrict__ Bw,
    _Float16* __restrict__ q16, _Float16* __restrict__ k16,
    _Float16* __restrict__ vt16)
{
    __shared__ __align__(16) _Float16 sm[2 * 128 * 64];  // 32 KB: sA | sB, reused as sT
    _Float16* sA = sm;
    _Float16* sB = sm + 128 * 64;
    const int tid = threadIdx.x;
    const int lane = tid & 63, wv = tid >> 6;
    const int quad = lane >> 4, l16 = lane & 15;
    const int wmh = wv >> 1, wnh = wv & 1;
    const int wm = wmh * 64, wn = wnh * 64;
    const int m0 = blockIdx.x * 128, n0 = blockIdx.y * 128;

    f32x4 acc[4][4] = {};

    for (int k0 = 0; k0 < NC; k0 += 64) {
        // stage, fragment-major: chunk P = f*64 + q*16 + l,
        // f = half*8 + t*2 + ksd -> row = half*64+t*16+l, kchunk = ksd*4+q
#pragma unroll
        for (int i = 0; i < 4; i++) {
            int P = tid + i * 256;
            int f = P >> 6, q = (P >> 4) & 3, l = P & 15;
            int half = f >> 3, t = (f >> 1) & 3, ksd = f & 1;
            int row = half * 64 + t * 16 + l;
            int ch = ksd * 4 + q;
            async16(Ah + (size_t)(m0 + row) * NC + k0 + ch * 8, sA + P * 8);
            async16(Bw + (size_t)(n0 + row) * NC + k0 + ch * 8, sB + P * 8);
        }
        __syncthreads();
#pragma unroll
        for (int ksd = 0; ksd < 2; ksd++) {
            f16x8 a4[4], b4[4];
#pragma unroll
            for (int t = 0; t < 4; t++) {
                a4[t] = *(const f16x8*)(sA + (((wmh * 4 + t) * 2 + ksd) * 64 + quad * 16 + l16) * 8);
                b4[t] = *(const f16x8*)(sB + (((wnh * 4 + t) * 2 + ksd) * 64 + quad * 16 + l16) * 8);
            }
#pragma unroll
            for (int i = 0; i < 4; i++)
#pragma unroll
                for (int j = 0; j < 4; j++)
                    acc[i][j] = __builtin_amdgcn_mfma_f32_16x16x32_f16(a4[i], b4[j], acc[i][j], 0, 0, 0);
        }
        __syncthreads();
    }

    // ---- epilogue via LDS transpose (sT = sm, 128x128 halves) ----
    _Float16* sT = sm;
    const bool is_v = (n0 >= 2 * NC);
    if (!is_v) {
        // sT[token'][col'] row-major stride 128
#pragma unroll
        for (int i = 0; i < 4; i++)
#pragma unroll
            for (int j = 0; j < 4; j++)
#pragma unroll
                for (int r = 0; r < 4; r++)
                    sT[(wm + i * 16 + quad * 4 + r) * 128 + wn + j * 16 + l16] =
                        (_Float16)acc[i][j][r];
        __syncthreads();
        int row = tid >> 1, hh = tid & 1;
        int grow = m0 + row, b = grow >> 10, nr = grow & 1023;
        int gc = n0 + hh * 64;
        int which = gc / NC, w2 = gc - which * NC, h = w2 >> 6;
        _Float16* dst = which ? k16 : q16;
        size_t base = ((size_t)((b * NH + h) * NN + nr)) * ND;
#pragma unroll
        for (int c = 0; c < 8; c++)
            *(f16x8*)(dst + base + c * 8) = *(const f16x8*)(sT + row * 128 + hh * 64 + c * 8);
    } else {
        // sT[col'][token'] (transposed write, f16x4 along tokens)
#pragma unroll
        for (int i = 0; i < 4; i++)
#pragma unroll
            for (int j = 0; j < 4; j++) {
                f16x4 v4;
                v4[0] = (_Float16)acc[i][j][0];
                v4[1] = (_Float16)acc[i][j][1];
                v4[2] = (_Float16)acc[i][j][2];
                v4[3] = (_Float16)acc[i][j][3];
                *(f16x4*)(sT + (wn + j * 16 + l16) * 128 + wm + i * 16 + quad * 4) = v4;
            }
        __syncthreads();
        int ch = tid >> 1, th = tid & 1;
        int w2 = n0 - 2 * NC + ch, h = w2 >> 6, dd = w2 & 63;
        int b = m0 >> 10, nr0 = (m0 & 1023) + th * 64;
        size_t base = ((size_t)((b * NH + h) * ND + dd)) * NN + nr0;
#pragma unroll
        for (int c = 0; c < 8; c++)
            *(f16x8*)(vt16 + base + c * 8) = *(const f16x8*)(sT + ch * 128 + th * 64 + c * 8);
    }
}

// ---------------- fused quadratic-ReLU attention (1-term QK) ----------------
// grid (8 q-tiles, 96 bh), 256 threads = 4 waves; wave handles 32 q-rows.
// S^T = K*Q^T; K-row assignment per fragment (ks2,T): lane i covers kv row
// ks2*32 + 8*(i>>2) + 4T + (i&3), so S^T acc (quad,l16,reg r) IS element
// (4T|r) of the PV B-fragment on the same lane (register re-pack).
// K and V^T staged in LDS fragment-major (0 bank conflicts).
// Output: hi/lo fp16 pair (proj stages it via global_load_lds).
__global__ __launch_bounds__(256) void attn_kernel(
    const _Float16* __restrict__ q16, const _Float16* __restrict__ k16,
    const _Float16* __restrict__ vt16,
    _Float16* __restrict__ ohA, _Float16* __restrict__ olA,
    const float* __restrict__ alpha, const float* __restrict__ beta,
    const float* __restrict__ gamma)
{
    const int qt = blockIdx.x, bh = blockIdx.y;
    const int b = bh / NH, h = bh - b * NH;
    const int tid = threadIdx.x, lane = tid & 63, wv = tid >> 6;
    const int quad = lane >> 4, l16 = lane & 15;
    const float a2 = alpha[h] * 0.015625f;   // alpha * SCALE^2
    const float b1 = beta[h] * 0.125f;       // beta * SCALE
    const float g0 = gamma[h];

    __shared__ __align__(16) _Float16 sKh[128 * 64];  // 16 KB, fragment-major
    __shared__ __align__(16) _Float16 sVt[64 * 128];  // 16 KB, fragment-major

    const _Float16* Qb = q16 + ((size_t)(bh * NN + qt * 128)) * ND;
    const _Float16* Kb = k16 + (size_t)bh * NN * ND;
    const _Float16* Vb = vt16 + (size_t)bh * ND * NN;

    f16x8 qf[2][2];
#pragma unroll
    for (int mt = 0; mt < 2; mt++)
#pragma unroll
        for (int ksd = 0; ksd < 2; ksd++)
            qf[mt][ksd] = *(const f16x8*)(Qb + (size_t)(wv * 32 + mt * 16 + l16) * ND
                                          + ksd * 32 + quad * 8);

    f32x4 O[4][2] = {};        // [dt][mt]
    float dsum[2] = {0.f, 0.f};

    for (int kt = 0; kt < 8; kt++) {
#pragma unroll
        for (int i = 0; i < 4; i++) {
            int P = tid + i * 256;
            int f = P >> 6, q = (P >> 4) & 3, a = (P >> 2) & 3, bb = P & 3;
            int ks2 = f >> 2, T = (f >> 1) & 1, ksd = f & 1;
            int row = ks2 * 32 + 8 * a + 4 * T + bb;
            async16(Kb + (size_t)(kt * 128 + row) * ND + (ksd * 4 + q) * 8, sKh + P * 8);
        }
#pragma unroll
        for (int i = 0; i < 4; i++) {
            int P = tid + i * 256;
            int f = P >> 6, q = (P >> 4) & 3, l = P & 15;
            int ks2 = f >> 2, dt = f & 3;
            async16(Vb + (size_t)(dt * 16 + l) * NN + kt * 128 + (ks2 * 4 + q) * 8,
                    sVt + P * 8);
        }
        __syncthreads();

        f16x8 bfrag[2][4];
#pragma unroll
        for (int T = 0; T < 2; T++) {
            f32x4 S[2][4] = {};
#pragma unroll
            for (int ks2 = 0; ks2 < 4; ks2++) {
#pragma unroll
                for (int ksd = 0; ksd < 2; ksd++) {
                    int addr = (((ks2 * 4 + T * 2 + ksd) * 64) + quad * 16 + l16) * 8;
                    f16x8 ah = *(const f16x8*)(sKh + addr);
#pragma unroll
                    for (int mt = 0; mt < 2; mt++)
                        S[mt][ks2] = __builtin_amdgcn_mfma_f32_16x16x32_f16(ah, qf[mt][ksd], S[mt][ks2], 0, 0, 0);
                }
            }
#pragma unroll
            for (int mt = 0; mt < 2; mt++) {
#pragma unroll
                for (int ks2 = 0; ks2 < 4; ks2++) {
#pragma unroll
                    for (int r = 0; r < 4; r++) {
                        float s = S[mt][ks2][r];
                        float w = fmaxf(fmaf(fmaf(a2, s, b1), s, g0), 0.f);
                        _Float16 wh = (_Float16)w;
                        dsum[mt] += (float)wh;
                        bfrag[mt][ks2][(T << 2) | r] = wh;
                    }
                }
            }
        }

#pragma unroll
        for (int ks2 = 0; ks2 < 4; ks2++) {
#pragma unroll
            for (int dt = 0; dt < 4; dt++) {
                int addr = (((ks2 * 4 + dt) * 64) + quad * 16 + l16) * 8;
                f16x8 vf = *(const f16x8*)(sVt + addr);
#pragma unroll
                for (int mt = 0; mt < 2; mt++)
                    O[dt][mt] = __builtin_amdgcn_mfma_f32_16x16x32_f16(vf, bfrag[mt][ks2], O[dt][mt], 0, 0, 0);
            }
        }
        __syncthreads();
    }

    float rinv[2];
#pragma unroll
    for (int mt = 0; mt < 2; mt++) {
        float v = dsum[mt];
        v += __shfl_xor(v, 16);
        v += __shfl_xor(v, 32);
        rinv[mt] = 1.0f / (v + 1e-6f);
    }

    // normalize + hi/lo split store (fp16 x2) to [B,N,H*d]
    const int base_row = qt * 128 + wv * 32;
#pragma unroll
    for (int dt = 0; dt < 4; dt++) {
#pragma unroll
        for (int mt = 0; mt < 2; mt++) {
            f16x4 h4, l4;
#pragma unroll
            for (int r = 0; r < 4; r++) {
                float v = O[dt][mt][r] * rinv[mt];
                _Float16 hv = (_Float16)v;
                h4[r] = hv;
                l4[r] = (_Float16)(v - (float)hv);
            }
            int row = base_row + mt * 16 + l16;                 // token n
            int col = h * ND + dt * 16 + quad * 4;              // channel c
            size_t addr = (size_t)(b * NN + row) * NC + col;
            *(f16x4*)(ohA + addr) = h4;
            *(f16x4*)(olA + addr) = l4;
        }
    }
}

// ---------------- proj GEMM: out = (Ah+Al) * (Bh+Bl)^T + bias, 3-term ----------------
// Tile 128x64, BK=64, fragment-major, all staging via global_load_lds.
__global__ __launch_bounds__(256) void gemm_proj(
    const _Float16* __restrict__ Ah, const _Float16* __restrict__ Al,
    const _Float16* __restrict__ Bh, const _Float16* __restrict__ Bl,
    const float* __restrict__ bias, float* __restrict__ out)
{
    __shared__ __align__(16) _Float16 sAh[128 * 64];  // 16 KB
    __shared__ __align__(16) _Float16 sAl[128 * 64];  // 16 KB
    __shared__ __align__(16) _Float16 sBh[64 * 64];   //  8 KB
    __shared__ __align__(16) _Float16 sBl[64 * 64];   //  8 KB
    const int tid = threadIdx.x;
    const int lane = tid & 63, wv = tid >> 6;
    const int quad = lane >> 4, l16 = lane & 15;
    const int wmh = wv >> 1, wnh = wv & 1;
    const int wm = wmh * 64, wn = wnh * 32;
    const int m0 = blockIdx.x * 128, n0 = blockIdx.y * 64;

    f32x4 acc[4][2] = {};

    for (int k0 = 0; k0 < NC; k0 += 64) {
        // A: 1024 chunks each (hi,lo), fragment-major
#pragma unroll
        for (int i = 0; i < 4; i++) {
            int P = tid + i * 256;
            int f = P >> 6, q = (P >> 4) & 3, l = P & 15;
            int half = f >> 3, t = (f >> 1) & 3, ksd = f & 1;
            int row = half * 64 + t * 16 + l;
            int ch = ksd * 4 + q;
            size_t src = (size_t)(m0 + row) * NC + k0 + ch * 8;
            async16(Ah + src, sAh + P * 8);
            async16(Al + src, sAl + P * 8);
        }
        // B: 512 chunks each (hi,lo), fragment-major f=(wnh,t,ksd)
#pragma unroll
        for (int i = 0; i < 2; i++) {
            int P = tid + i * 256;
            int f = P >> 6, q = (P >> 4) & 3, l = P & 15;
            int nh = f >> 2, t = (f >> 1) & 1, ksd = f & 1;
            int row = nh * 32 + t * 16 + l;
            int ch = ksd * 4 + q;
            size_t src = (size_t)(n0 + row) * NC + k0 + ch * 8;
            async16(Bh + src, sBh + P * 8);
            async16(Bl + src, sBl + P * 8);
        }
        __syncthreads();
#pragma unroll
        for (int ksd = 0; ksd < 2; ksd++) {
            f16x8 a4[4], a4l[4], b4[2], b4l[2];
#pragma unroll
            for (int t = 0; t < 4; t++) {
                int addr = (((wmh * 4 + t) * 2 + ksd) * 64 + quad * 16 + l16) * 8;
                a4[t]  = *(const f16x8*)(sAh + addr);
                a4l[t] = *(const f16x8*)(sAl + addr);
            }
#pragma unroll
            for (int t = 0; t < 2; t++) {
                int addr = (((wnh * 2 + t) * 2 + ksd) * 64 + quad * 16 + l16) * 8;
                b4[t]  = *(const f16x8*)(sBh + addr);
                b4l[t] = *(const f16x8*)(sBl + addr);
            }
#pragma unroll
            for (int i = 0; i < 4; i++)
#pragma unroll
                for (int j = 0; j < 2; j++)
                    acc[i][j] = __builtin_amdgcn_mfma_f32_16x16x32_f16(a4[i], b4[j], acc[i][j], 0, 0, 0);
#pragma unroll
            for (int i = 0; i < 4; i++)
#pragma unroll
                for (int j = 0; j < 2; j++)
                    acc[i][j] = __builtin_amdgcn_mfma_f32_16x16x32_f16(a4l[i], b4[j], acc[i][j], 0, 0, 0);
#pragma unroll
            for (int i = 0; i < 4; i++)
#pragma unroll
                for (int j = 0; j < 2; j++)
                    acc[i][j] = __builtin_amdgcn_mfma_f32_16x16x32_f16(a4[i], b4l[j], acc[i][j], 0, 0, 0);
        }
        __syncthreads();
    }

#pragma unroll
    for (int i = 0; i < 4; i++) {
#pragma unroll
        for (int j = 0; j < 2; j++) {
#pragma unroll
            for (int r = 0; r < 4; r++) {
                int row = m0 + wm + i * 16 + quad * 4 + r;
                int col = n0 + wn + j * 16 + l16;
                out[(size_t)row * NC + col] = acc[i][j][r] + bias[col];
            }
        }
    }
}

// ---------------- launch ----------------
extern "C" void kernel_launch(void* const* d_in, const int* in_sizes, int n_in,
                              void* d_out, int out_size, void* d_ws, size_t ws_size,
                              hipStream_t stream) {
    const float* x      = (const float*)d_in[0];
    const float* w_qkv  = (const float*)d_in[1];
    const float* w_proj = (const float*)d_in[2];
    const float* b_proj = (const float*)d_in[3];
    const float* alpha  = (const float*)d_in[4];
    const float* beta   = (const float*)d_in[5];
    const float* gamma  = (const float*)d_in[6];
    float* out = (float*)d_out;

    char* ws = (char*)d_ws;
    _Float16* ohA    = (_Float16*)(ws + 0);            // 12,582,912 B
    _Float16* olA    = (_Float16*)(ws + 12582912);     // 12,582,912 B
    _Float16* xh     = (_Float16*)(ws + 25165824);     // 12,582,912 B
    _Float16* wqkvh  = (_Float16*)(ws + 37748736);     //  3,538,944 B
    _Float16* wprojh = (_Float16*)(ws + 41287680);     //  1,179,648 B
    _Float16* wprojl = (_Float16*)(ws + 42467328);     //  1,179,648 B
    _Float16* q16    = (_Float16*)(ws + 43646976);     // 12,582,912 B
    _Float16* k16    = (_Float16*)(ws + 56229888);     // 12,582,912 B
    _Float16* vt16   = (_Float16*)(ws + 68812800);     // ends 81,395,712 B

    cvt_f32_f16<<<6144, 256, 0, stream>>>(x, xh, 1572864);
    cvt_f32_f16<<<1728, 256, 0, stream>>>(w_qkv, wqkvh, 442368);
    cvt_split_f32<<<576, 256, 0, stream>>>(w_proj, wprojh, wprojl, 147456);

    gemm_qkv<<<dim3(64, 18), 256, 0, stream>>>(xh, wqkvh, q16, k16, vt16);
    attn_kernel<<<dim3(8, 96), 256, 0, stream>>>(q16, k16, vt16, ohA, olA, alpha, beta, gamma);
    gemm_proj<<<dim3(64, 12), 256, 0, stream>>>(ohA, olA, wprojh, wprojl, b_proj, out);
}